// Round 1
// baseline (1892.633 us; speedup 1.0000x reference)
//
#include <hip/hip_runtime.h>
#include <cstdint>

typedef unsigned short u16;
typedef short s16x8 __attribute__((ext_vector_type(8)));
typedef float f32x4 __attribute__((ext_vector_type(4)));
typedef unsigned short u16x4 __attribute__((ext_vector_type(4)));

#define LDK 4224   // K total = 4096 (x) + 128 (lora)
#define KX  4096
#define BT  8192
#define OUT_D 4096

// ---------- helpers ----------
__device__ __forceinline__ u16 bf16_rne(float v) {
  unsigned u = __float_as_uint(v);
  return (u16)((u + 0x7FFFu + ((u >> 16) & 1u)) >> 16);
}
__device__ __forceinline__ float bf16_f(u16 h) { return __uint_as_float(((unsigned)h) << 16); }

// global -> LDS direct copy, 16B per lane. dst must be wave-uniform; lane writes at +lane*16.
__device__ __forceinline__ void gl16(const void* g, void* l) {
  auto gp = reinterpret_cast<const __attribute__((address_space(1))) unsigned int*>(
      reinterpret_cast<uintptr_t>(g));
  auto lp = reinterpret_cast<__attribute__((address_space(3))) unsigned int*>(
      reinterpret_cast<uintptr_t>(l));
  __builtin_amdgcn_global_load_lds(gp, lp, 16, 0, 0);
}

// ---------- kernel 1: per-token router + h, also emits x as bf16 hi/lo ----------
// fast=1: write Xh/Xl rows [t][0..4223] (x split + h*w*SCALING split)
// fast=0: write hwf[t][0..127] = h*w*SCALING as fp32 (fallback path)
__global__ __launch_bounds__(256) void k_router(
    const float* __restrict__ x, const float* __restrict__ rW, const float* __restrict__ rb,
    const float* __restrict__ A, const int* __restrict__ emap,
    u16* __restrict__ Xh, u16* __restrict__ Xl, float* __restrict__ hwf, int fast)
{
  __shared__ float4 xs4[1024];
  __shared__ float outs[144];   // 0..14 logits, 15..142 h
  __shared__ float wsc[8];
  const int t = blockIdx.x;
  const int tid = threadIdx.x;
  const float4* xr = (const float4*)(x + (size_t)t * 4096);
  float4 xv[4];
#pragma unroll
  for (int i = 0; i < 4; ++i) { xv[i] = xr[tid + i * 256]; xs4[tid + i * 256] = xv[i]; }
  __syncthreads();

  if (fast) {
#pragma unroll
    for (int i = 0; i < 4; ++i) {
      const int e0 = (tid + i * 256) * 4;
      float vv[4] = {xv[i].x, xv[i].y, xv[i].z, xv[i].w};
      u16x4 hv, lv;
#pragma unroll
      for (int j = 0; j < 4; ++j) {
        u16 h = bf16_rne(vv[j]);
        u16 l = bf16_rne(vv[j] - bf16_f(h));
        hv[j] = h; lv[j] = l;
      }
      *(u16x4*)&Xh[(size_t)t * LDK + e0] = hv;
      *(u16x4*)&Xl[(size_t)t * LDK + e0] = lv;
    }
  }

  const int lane = tid & 63, wid = tid >> 6;
  const float* xs = (const float*)xs4;
  for (int o = wid; o < 143; o += 4) {
    const float4* wrow = (const float4*)((o < 15) ? (rW + (size_t)o * 4096)
                                                  : (A + (size_t)(o - 15) * 4096));
    float s = 0.f;
    for (int i = lane; i < 1024; i += 64) {
      float4 a = ((const float4*)xs)[i];
      float4 w = wrow[i];
      s = fmaf(a.x, w.x, fmaf(a.y, w.y, fmaf(a.z, w.z, fmaf(a.w, w.w, s))));
    }
#pragma unroll
    for (int off = 32; off; off >>= 1) s += __shfl_down(s, off, 64);
    if (lane == 0) outs[o] = s + ((o < 15) ? rb[o] : 0.f);
  }
  __syncthreads();

  if (tid == 0) {
    float p[15];
    float mx = outs[0];
#pragma unroll
    for (int i = 1; i < 15; ++i) mx = fmaxf(mx, outs[i]);
    float sum = 0.f;
#pragma unroll
    for (int i = 0; i < 15; ++i) { p[i] = __expf(outs[i] - mx); sum += p[i]; }
    const float inv = 1.f / sum;
    float w[8] = {0, 0, 0, 0, 0, 0, 0, 0};
    unsigned sel = 0;
    for (int j = 0; j < 8; ++j) {       // top-8 of 15, ties -> lowest index (matches lax.top_k)
      int bi = -1; float bv = -1.f;
      for (int i = 0; i < 15; ++i)
        if (!((sel >> i) & 1u) && p[i] > bv) { bv = p[i]; bi = i; }
      sel |= 1u << bi;
      w[emap[bi]] += p[bi] * inv;
    }
#pragma unroll
    for (int e = 0; e < 8; ++e) wsc[e] = w[e] * 2.0f;   // SCALING = 32/16
  }
  __syncthreads();

  if (tid < 128) {
    const float hv = outs[15 + tid] * wsc[tid >> 4];
    if (fast) {
      u16 h = bf16_rne(hv);
      u16 l = bf16_rne(hv - bf16_f(h));
      const size_t off = (size_t)t * LDK + KX + tid;
      Xh[off] = h; Xl[off] = l;
    } else {
      hwf[(size_t)t * 128 + tid] = hv;
    }
  }
}

// ---------- kernel 2: split base_W (4096x4096 fp32) into Wh/Wl cols 0..4095 ----------
__global__ __launch_bounds__(256) void k_split_w(
    const float* __restrict__ src, u16* __restrict__ dh, u16* __restrict__ dl, int nquad)
{
  for (long i = (long)blockIdx.x * 256 + threadIdx.x; i < nquad; i += (long)gridDim.x * 256) {
    float4 v = ((const float4*)src)[i];
    long e = i * 4;
    int r = (int)(e >> 12);
    int c = (int)(e & 4095);
    float vv[4] = {v.x, v.y, v.z, v.w};
    u16x4 hv, lv;
#pragma unroll
    for (int j = 0; j < 4; ++j) {
      u16 h = bf16_rne(vv[j]);
      u16 l = bf16_rne(vv[j] - bf16_f(h));
      hv[j] = h; lv[j] = l;
    }
    size_t o = (size_t)r * LDK + c;
    *(u16x4*)&dh[o] = hv;
    *(u16x4*)&dl[o] = lv;
  }
}

// ---------- kernel 3: B [E=8][O=4096][R=16] -> W cols 4096..4223 (or fp32 Bt fallback) ----------
__global__ __launch_bounds__(256) void k_bt(
    const float* __restrict__ B, u16* __restrict__ dh, u16* __restrict__ dl,
    float* __restrict__ btf, int fast)
{
  const int idx = blockIdx.x * 256 + threadIdx.x;
  if (idx >= 8 * 4096 * 16) return;
  const int e = idx >> 16;
  const int rem = idx & 65535;
  const int o = rem >> 4;
  const int r = rem & 15;
  const float v = B[idx];
  if (fast) {
    u16 h = bf16_rne(v);
    u16 l = bf16_rne(v - bf16_f(h));
    const size_t off = (size_t)o * LDK + KX + e * 16 + r;
    dh[off] = h; dl[off] = l;
  } else {
    btf[o * 128 + e * 16 + r] = v;
  }
}

// ---------- kernel 4: bf16x3 GEMM: out[8192][4096] = (Xh+Xl)·(Wh+Wl)^T + bias ----------
// 128x128 tile, BK=32, 4 waves, mfma_f32_16x16x32_bf16, m97-style 2-barrier loop.
__global__ __launch_bounds__(256) void k_gemm(
    const u16* __restrict__ Xh, const u16* __restrict__ Xl,
    const u16* __restrict__ Wh, const u16* __restrict__ Wl,
    const float* __restrict__ bias, float* __restrict__ out)
{
  __shared__ __align__(16) u16 lAh[4096], lAl[4096], lBh[4096], lBl[4096];
  const int tid = threadIdx.x;
  const int lane = tid & 63;
  const int wid = tid >> 6;

  // bijective XCD swizzle (gridDim.x = 2048, % 8 == 0)
  const int bI = blockIdx.x;
  const int cpx = gridDim.x >> 3;
  const int wg = (bI & 7) * cpx + (bI >> 3);
  const int bm = wg >> 5;            // 64 M-tiles
  const int bn = wg & 31;            // 32 N-tiles
  const int wr = wid >> 1, wc = wid & 1;

  // staging map: thread i -> row i/4, 8 elems at (i%4)*8 of the [128][32] tile
  const int srow = tid >> 2;
  const int skc = (tid & 3) << 3;
  const size_t a0 = (size_t)(bm * 128 + srow) * LDK + skc;
  const size_t a1 = a0 + (size_t)64 * LDK;
  const size_t b0 = (size_t)(bn * 128 + srow) * LDK + skc;
  const size_t b1 = b0 + (size_t)64 * LDK;
  const int d0 = wid * 512;          // elems; per-wave uniform LDS base (bytes wid*1024)
  const int d1 = 2048 + wid * 512;

  // fragment addresses: A row = wr*64 + m*16 + (lane&15); k = (lane>>4)*8 + j (consecutive 8)
  const int ra = (wr * 64 + (lane & 15)) * 32 + ((lane >> 4) << 3);
  const int rb = (wc * 64 + (lane & 15)) * 32 + ((lane >> 4) << 3);

  f32x4 acc[4][4] = {};

  for (int kt = 0; kt < 132; ++kt) {
    const int ko = kt * 32;
    gl16(Xh + a0 + ko, lAh + d0);
    gl16(Xh + a1 + ko, lAh + d1);
    gl16(Xl + a0 + ko, lAl + d0);
    gl16(Xl + a1 + ko, lAl + d1);
    gl16(Wh + b0 + ko, lBh + d0);
    gl16(Wh + b1 + ko, lBh + d1);
    gl16(Wl + b0 + ko, lBl + d0);
    gl16(Wl + b1 + ko, lBl + d1);
    asm volatile("s_waitcnt vmcnt(0)" ::: "memory");
    __syncthreads();

    s16x8 ah[4], al[4], bh[4], bl[4];
#pragma unroll
    for (int m = 0; m < 4; ++m) {
      ah[m] = *(const s16x8*)&lAh[ra + m * 512];
      al[m] = *(const s16x8*)&lAl[ra + m * 512];
    }
#pragma unroll
    for (int n = 0; n < 4; ++n) {
      bh[n] = *(const s16x8*)&lBh[rb + n * 512];
      bl[n] = *(const s16x8*)&lBl[rb + n * 512];
    }
#pragma unroll
    for (int m = 0; m < 4; ++m)
#pragma unroll
      for (int n = 0; n < 4; ++n) {
        acc[m][n] = __builtin_amdgcn_mfma_f32_16x16x32_bf16(ah[m], bh[n], acc[m][n], 0, 0, 0);
        acc[m][n] = __builtin_amdgcn_mfma_f32_16x16x32_bf16(ah[m], bl[n], acc[m][n], 0, 0, 0);
        acc[m][n] = __builtin_amdgcn_mfma_f32_16x16x32_bf16(al[m], bh[n], acc[m][n], 0, 0, 0);
      }
    __syncthreads();
  }

  // epilogue: C/D layout col=lane&15, row=(lane>>4)*4+r  (m89-verified)
  const int orow = bm * 128 + wr * 64 + ((lane >> 4) << 2);
  const int ocol = bn * 128 + wc * 64 + (lane & 15);
#pragma unroll
  for (int n = 0; n < 4; ++n) {
    const float bv = bias[ocol + n * 16];
#pragma unroll
    for (int m = 0; m < 4; ++m)
#pragma unroll
      for (int r = 0; r < 4; ++r)
        out[(size_t)(orow + m * 16 + r) * OUT_D + ocol + n * 16] = acc[m][n][r] + bv;
  }
}

// ---------- fallback fp32 GEMM (used only if ws too small for split operands) ----------
__global__ __launch_bounds__(256) void k_gemm_fb(
    const float* __restrict__ X, const float* __restrict__ W, const float* __restrict__ bias,
    const float* __restrict__ hwf, const float* __restrict__ btf, float* __restrict__ out)
{
  __shared__ float sA[64][33], sB[64][33];
  const int bm = blockIdx.x >> 6;    // 128 M-tiles of 64
  const int bn = blockIdx.x & 63;    // 64 N-tiles of 64
  const int tid = threadIdx.x;
  const int tr = tid >> 4, tc = tid & 15;
  float acc[4][4] = {};

  const float* Aps[2] = {X, hwf};
  const float* Bps[2] = {W, btf};
  const int lds_[2] = {4096, 128};
  const int Ks[2] = {4096, 128};

  for (int ph = 0; ph < 2; ++ph) {
    const float* Ap = Aps[ph];
    const float* Bp = Bps[ph];
    const int ld = lds_[ph];
    for (int k0 = 0; k0 < Ks[ph]; k0 += 32) {
      __syncthreads();
      for (int i = tid; i < 512; i += 256) {
        const int r = i >> 3, c = (i & 7) << 2;
        float4 va = *(const float4*)&Ap[(size_t)(bm * 64 + r) * ld + k0 + c];
        sA[r][c] = va.x; sA[r][c + 1] = va.y; sA[r][c + 2] = va.z; sA[r][c + 3] = va.w;
        float4 vb = *(const float4*)&Bp[(size_t)(bn * 64 + r) * ld + k0 + c];
        sB[r][c] = vb.x; sB[r][c + 1] = vb.y; sB[r][c + 2] = vb.z; sB[r][c + 3] = vb.w;
      }
      __syncthreads();
      for (int k = 0; k < 32; ++k) {
        float a[4], bvv[4];
#pragma unroll
        for (int i = 0; i < 4; ++i) a[i] = sA[tr * 4 + i][k];
#pragma unroll
        for (int j = 0; j < 4; ++j) bvv[j] = sB[tc * 4 + j][k];
#pragma unroll
        for (int i = 0; i < 4; ++i)
#pragma unroll
          for (int j = 0; j < 4; ++j) acc[i][j] = fmaf(a[i], bvv[j], acc[i][j]);
      }
    }
  }
#pragma unroll
  for (int i = 0; i < 4; ++i)
#pragma unroll
    for (int j = 0; j < 4; ++j)
      out[(size_t)(bm * 64 + tr * 4 + i) * OUT_D + bn * 64 + tc * 4 + j] =
          acc[i][j] + bias[bn * 64 + tc * 4 + j];
}

// ---------- launch ----------
extern "C" void kernel_launch(void* const* d_in, const int* in_sizes, int n_in,
                              void* d_out, int out_size, void* d_ws, size_t ws_size,
                              hipStream_t stream) {
  const float* x   = (const float*)d_in[0];
  const float* bW  = (const float*)d_in[1];
  const float* bb  = (const float*)d_in[2];
  const float* rW  = (const float*)d_in[3];
  const float* rb  = (const float*)d_in[4];
  const float* A   = (const float*)d_in[5];
  const float* Bm  = (const float*)d_in[6];
  const int*   emap = (const int*)d_in[7];
  float* out = (float*)d_out;

  const size_t SZ_X = (size_t)BT * LDK * 2;      // 69,206,016 B each
  const size_t SZ_W = (size_t)OUT_D * LDK * 2;   // 34,603,008 B each
  const size_t need = 2 * SZ_X + 2 * SZ_W;       // ~198 MB
  char* ws = (char*)d_ws;

  if (ws_size >= need) {
    u16* Xh = (u16*)ws;
    u16* Xl = (u16*)(ws + SZ_X);
    u16* Wh = (u16*)(ws + 2 * SZ_X);
    u16* Wl = (u16*)(ws + 2 * SZ_X + SZ_W);
    k_router<<<dim3(BT), dim3(256), 0, stream>>>(x, rW, rb, A, emap, Xh, Xl, nullptr, 1);
    k_split_w<<<dim3(4096), dim3(256), 0, stream>>>(bW, Wh, Wl, 4096 * 4096 / 4);
    k_bt<<<dim3(2048), dim3(256), 0, stream>>>(Bm, Wh, Wl, nullptr, 1);
    k_gemm<<<dim3(2048), dim3(256), 0, stream>>>(Xh, Xl, Wh, Wl, bb, out);
  } else {
    float* hwf = (float*)ws;                            // 4 MB
    float* btf = (float*)(ws + (size_t)BT * 128 * 4);   // 2 MB
    k_router<<<dim3(BT), dim3(256), 0, stream>>>(x, rW, rb, A, emap, nullptr, nullptr, hwf, 0);
    k_bt<<<dim3(2048), dim3(256), 0, stream>>>(Bm, nullptr, nullptr, btf, 0);
    k_gemm_fb<<<dim3(8192), dim3(256), 0, stream>>>(x, bW, bb, hwf, btf, out);
  }
}

// Round 4
// 1497.730 us; speedup vs baseline: 1.2637x; 1.2637x over previous
//
#include <hip/hip_runtime.h>
#include <cstdint>

typedef unsigned short u16;
typedef short s16x8 __attribute__((ext_vector_type(8)));
typedef float f32x4 __attribute__((ext_vector_type(4)));
typedef unsigned short u16x4 __attribute__((ext_vector_type(4)));

#define KX    4096
#define BT    8192
#define OUT_D 4096
#define NW    4224           // GEMM1 N: 4096 base rows + 128 A rows

// ---------- helpers ----------
__device__ __forceinline__ u16 bf16_rne(float v) {
  unsigned u = __float_as_uint(v);
  return (u16)((u + 0x7FFFu + ((u >> 16) & 1u)) >> 16);
}
__device__ __forceinline__ float bf16_f(u16 h) { return __uint_as_float(((unsigned)h) << 16); }

__device__ __forceinline__ void gl16(const void* g, void* l) {
  auto gp = reinterpret_cast<const __attribute__((address_space(1))) unsigned int*>(
      reinterpret_cast<uintptr_t>(g));
  auto lp = reinterpret_cast<__attribute__((address_space(3))) unsigned int*>(
      reinterpret_cast<uintptr_t>(l));
  __builtin_amdgcn_global_load_lds(gp, lp, 16, 0, 0);
}

// softmax over 15 logits + top-8 + expert combine weights (×SCALING=2)
__device__ __forceinline__ void route_w(const float* s, const float* rb,
                                        const int* emap, float* wsc, int t) {
  float p[15]; float mx = -1e30f;
#pragma unroll
  for (int i = 0; i < 15; ++i) { p[i] = s[i] + rb[i]; mx = fmaxf(mx, p[i]); }
  float sum = 0.f;
#pragma unroll
  for (int i = 0; i < 15; ++i) { p[i] = __expf(p[i] - mx); sum += p[i]; }
  const float inv = 1.f / sum;
  float w[8] = {0, 0, 0, 0, 0, 0, 0, 0};
  unsigned sel = 0;
  for (int j = 0; j < 8; ++j) {          // top-8 of 15; strict > keeps first index on ties
    int bi = -1; float bv = -1.f;
    for (int i = 0; i < 15; ++i)
      if (!((sel >> i) & 1u) && p[i] > bv) { bv = p[i]; bi = i; }
    sel |= 1u << bi;
    w[emap[bi]] += p[bi] * inv;
  }
#pragma unroll
  for (int e = 0; e < 8; ++e) wsc[t * 8 + e] = w[e] * 2.0f;
}

// ---------- k_split_x: x -> Xh/Xl, fused router logits -> wsc ----------
// 1024 blocks x 256 threads; block = 8 tokens.
__global__ __launch_bounds__(256) void k_split_x(
    const float* __restrict__ x, const float* __restrict__ rW, const float* __restrict__ rb,
    const int* __restrict__ emap,
    u16* __restrict__ Xh, u16* __restrict__ Xl, float* __restrict__ wsc)
{
  const int tid = threadIdx.x;
  const int blk = blockIdx.x;

  // phase 1: convert 8 tokens = 8192 float4
  const float4* xs = (const float4*)x + (size_t)blk * 8192;
#pragma unroll 4
  for (int j = 0; j < 32; ++j) {
    const int i = j * 256 + tid;
    float4 v = xs[i];
    float vv[4] = {v.x, v.y, v.z, v.w};
    u16x4 hv, lv;
#pragma unroll
    for (int q = 0; q < 4; ++q) {
      u16 h = bf16_rne(vv[q]);
      hv[q] = h; lv[q] = bf16_rne(vv[q] - bf16_f(h));
    }
    const size_t e0 = ((size_t)blk * 8192 + i) * 4;
    *(u16x4*)&Xh[e0] = hv;
    *(u16x4*)&Xl[e0] = lv;
  }

  // phase 2: 15 router logits; wave handles 2 tokens
  const int lane = tid & 63, wid = tid >> 6;
  const int t0 = blk * 8 + wid * 2;
  const float4* xr0 = (const float4*)x + (size_t)t0 * 1024;
  const float4* xr1 = xr0 + 1024;
  const float4* w4 = (const float4*)rW;
  float s0[15], s1[15];
#pragma unroll
  for (int o = 0; o < 15; ++o) { s0[o] = 0.f; s1[o] = 0.f; }
  for (int it = 0; it < 16; ++it) {
    const int off = it * 64 + lane;
    float4 xa = xr0[off];
    float4 xb = xr1[off];
#pragma unroll
    for (int o = 0; o < 15; ++o) {
      float4 w = w4[o * 1024 + off];
      s0[o] = fmaf(xa.x, w.x, fmaf(xa.y, w.y, fmaf(xa.z, w.z, fmaf(xa.w, w.w, s0[o]))));
      s1[o] = fmaf(xb.x, w.x, fmaf(xb.y, w.y, fmaf(xb.z, w.z, fmaf(xb.w, w.w, s1[o]))));
    }
  }
#pragma unroll
  for (int o = 0; o < 15; ++o) {
#pragma unroll
    for (int d = 32; d; d >>= 1) {
      s0[o] += __shfl_down(s0[o], d, 64);
      s1[o] += __shfl_down(s1[o], d, 64);
    }
  }
  if (lane == 0) {
    route_w(s0, rb, emap, wsc, t0);
    route_w(s1, rb, emap, wsc, t0 + 1);
  }
}

// ---------- k_split_w: [base_W(4096) ; A(128)] -> Wh/Wl [4224][4096] ----------
__global__ __launch_bounds__(256) void k_split_w(
    const float* __restrict__ bW, const float* __restrict__ A,
    u16* __restrict__ dh, u16* __restrict__ dl)
{
  const long n4 = (long)NW * KX / 4;       // float4 count
  for (long i = (long)blockIdx.x * 256 + threadIdx.x; i < n4; i += (long)gridDim.x * 256) {
    float4 v = (i < 4194304) ? ((const float4*)bW)[i] : ((const float4*)A)[i - 4194304];
    float vv[4] = {v.x, v.y, v.z, v.w};
    u16x4 hv, lv;
#pragma unroll
    for (int j = 0; j < 4; ++j) {
      u16 h = bf16_rne(vv[j]);
      hv[j] = h; lv[j] = bf16_rne(vv[j] - bf16_f(h));
    }
    *(u16x4*)&dh[i * 4] = hv;
    *(u16x4*)&dl[i * 4] = lv;
  }
}

// ---------- k_bt: B [8][4096][16] -> Bt [4096][128] hi/lo (fast) or fp32 (fallback) ----------
__global__ __launch_bounds__(256) void k_bt(
    const float* __restrict__ B, u16* __restrict__ dh, u16* __restrict__ dl,
    float* __restrict__ btf, int fast)
{
  const int idx = blockIdx.x * 256 + threadIdx.x;
  if (idx >= 8 * 4096 * 16) return;
  const int e = idx >> 16;
  const int o = (idx >> 4) & 4095;
  const int r = idx & 15;
  const float v = B[idx];
  const int off = o * 128 + e * 16 + r;
  if (fast) {
    u16 h = bf16_rne(v);
    dh[off] = h; dl[off] = bf16_rne(v - bf16_f(h));
  } else {
    btf[off] = v;
  }
}

// ---------- k_gemm1: [out | h] = X · W^T (bf16x3), 128x128 tile, BK=32 ----------
__global__ __launch_bounds__(256) void k_gemm1(
    const u16* __restrict__ Xh, const u16* __restrict__ Xl,
    const u16* __restrict__ Wh, const u16* __restrict__ Wl,
    const float* __restrict__ bias, const float* __restrict__ wsc,
    float* __restrict__ out, u16* __restrict__ XLh, u16* __restrict__ XLl)
{
  __shared__ __align__(16) u16 lAh[4096], lAl[4096], lBh[4096], lBl[4096];
  const int tid = threadIdx.x;
  const int lane = tid & 63;
  const int wid = tid >> 6;

  // bijective XCD swizzle (grid = 2112, 2112 % 8 == 0)
  const int bI = blockIdx.x;
  const int cpx = gridDim.x >> 3;
  const int wg = (bI & 7) * cpx + (bI >> 3);
  const int bm = wg / 33;            // 64 M-tiles
  const int bn = wg % 33;            // 33 N-tiles (32 base + 1 lora-h)
  const int wr = wid >> 1, wc = wid & 1;

  const int srow = tid >> 2;
  const int skc = (tid & 3) << 3;
  const size_t a0 = (size_t)(bm * 128 + srow) * KX + skc;
  const size_t a1 = a0 + (size_t)64 * KX;
  const size_t b0 = (size_t)(bn * 128 + srow) * KX + skc;
  const size_t b1 = b0 + (size_t)64 * KX;
  const int d0 = wid * 512;
  const int d1 = 2048 + wid * 512;

  const int ra = (wr * 64 + (lane & 15)) * 32 + ((lane >> 4) << 3);
  const int rb = (wc * 64 + (lane & 15)) * 32 + ((lane >> 4) << 3);

  f32x4 acc[4][4] = {};

  for (int kt = 0; kt < 128; ++kt) {
    const int ko = kt * 32;
    gl16(Xh + a0 + ko, lAh + d0);
    gl16(Xh + a1 + ko, lAh + d1);
    gl16(Xl + a0 + ko, lAl + d0);
    gl16(Xl + a1 + ko, lAl + d1);
    gl16(Wh + b0 + ko, lBh + d0);
    gl16(Wh + b1 + ko, lBh + d1);
    gl16(Wl + b0 + ko, lBl + d0);
    gl16(Wl + b1 + ko, lBl + d1);
    asm volatile("s_waitcnt vmcnt(0)" ::: "memory");
    __syncthreads();

    s16x8 ah[4], al[4], bh[4], bl[4];
#pragma unroll
    for (int m = 0; m < 4; ++m) {
      ah[m] = *(const s16x8*)&lAh[ra + m * 512];
      al[m] = *(const s16x8*)&lAl[ra + m * 512];
    }
#pragma unroll
    for (int n = 0; n < 4; ++n) {
      bh[n] = *(const s16x8*)&lBh[rb + n * 512];
      bl[n] = *(const s16x8*)&lBl[rb + n * 512];
    }
#pragma unroll
    for (int m = 0; m < 4; ++m)
#pragma unroll
      for (int n = 0; n < 4; ++n) {
        acc[m][n] = __builtin_amdgcn_mfma_f32_16x16x32_bf16(ah[m], bh[n], acc[m][n], 0, 0, 0);
        acc[m][n] = __builtin_amdgcn_mfma_f32_16x16x32_bf16(ah[m], bl[n], acc[m][n], 0, 0, 0);
        acc[m][n] = __builtin_amdgcn_mfma_f32_16x16x32_bf16(al[m], bh[n], acc[m][n], 0, 0, 0);
      }
    __syncthreads();
  }

  // epilogue: C/D layout col=lane&15, row=(lane>>4)*4+r (m89-verified)
  const int orow = bm * 128 + wr * 64 + ((lane >> 4) << 2);
  const int ocol = bn * 128 + wc * 64 + (lane & 15);
  if (bn < 32) {
#pragma unroll
    for (int n = 0; n < 4; ++n) {
      const float bv = bias[ocol + n * 16];
#pragma unroll
      for (int m = 0; m < 4; ++m)
#pragma unroll
        for (int r = 0; r < 4; ++r)
          out[(size_t)(orow + m * 16 + r) * OUT_D + ocol + n * 16] = acc[m][n][r] + bv;
    }
  } else {
    // h columns: j = e*16+r index into XL, scaled by wsc[t][e]
#pragma unroll
    for (int n = 0; n < 4; ++n) {
      const int j = ocol + n * 16 - KX;      // 0..127
      const int e = j >> 4;
#pragma unroll
      for (int m = 0; m < 4; ++m)
#pragma unroll
        for (int r = 0; r < 4; ++r) {
          const int t = orow + m * 16 + r;
          const float v = acc[m][n][r] * wsc[t * 8 + e];
          u16 h = bf16_rne(v);
          XLh[t * 128 + j] = h;
          XLl[t * 128 + j] = bf16_rne(v - bf16_f(h));
        }
    }
  }
}

// ---------- k_gemm2: out += XL · Bt^T (bf16x3), K=128 ----------
__global__ __launch_bounds__(256) void k_gemm2(
    const u16* __restrict__ XLh, const u16* __restrict__ XLl,
    const u16* __restrict__ Bth, const u16* __restrict__ Btl,
    float* __restrict__ out)
{
  __shared__ __align__(16) u16 lAh[4096], lAl[4096], lBh[4096], lBl[4096];
  const int tid = threadIdx.x;
  const int lane = tid & 63;
  const int wid = tid >> 6;

  const int bI = blockIdx.x;
  const int cpx = gridDim.x >> 3;
  const int wg = (bI & 7) * cpx + (bI >> 3);
  const int bm = wg >> 5;            // 64 M-tiles
  const int bn = wg & 31;            // 32 N-tiles
  const int wr = wid >> 1, wc = wid & 1;

  const int srow = tid >> 2;
  const int skc = (tid & 3) << 3;
  const size_t a0 = (size_t)(bm * 128 + srow) * 128 + skc;
  const size_t a1 = a0 + (size_t)64 * 128;
  const size_t b0 = (size_t)(bn * 128 + srow) * 128 + skc;
  const size_t b1 = b0 + (size_t)64 * 128;
  const int d0 = wid * 512;
  const int d1 = 2048 + wid * 512;

  const int ra = (wr * 64 + (lane & 15)) * 32 + ((lane >> 4) << 3);
  const int rb = (wc * 64 + (lane & 15)) * 32 + ((lane >> 4) << 3);

  f32x4 acc[4][4] = {};

  for (int kt = 0; kt < 4; ++kt) {
    const int ko = kt * 32;
    gl16(XLh + a0 + ko, lAh + d0);
    gl16(XLh + a1 + ko, lAh + d1);
    gl16(XLl + a0 + ko, lAl + d0);
    gl16(XLl + a1 + ko, lAl + d1);
    gl16(Bth + b0 + ko, lBh + d0);
    gl16(Bth + b1 + ko, lBh + d1);
    gl16(Btl + b0 + ko, lBl + d0);
    gl16(Btl + b1 + ko, lBl + d1);
    asm volatile("s_waitcnt vmcnt(0)" ::: "memory");
    __syncthreads();

    s16x8 ah[4], al[4], bh[4], bl[4];
#pragma unroll
    for (int m = 0; m < 4; ++m) {
      ah[m] = *(const s16x8*)&lAh[ra + m * 512];
      al[m] = *(const s16x8*)&lAl[ra + m * 512];
    }
#pragma unroll
    for (int n = 0; n < 4; ++n) {
      bh[n] = *(const s16x8*)&lBh[rb + n * 512];
      bl[n] = *(const s16x8*)&lBl[rb + n * 512];
    }
#pragma unroll
    for (int m = 0; m < 4; ++m)
#pragma unroll
      for (int n = 0; n < 4; ++n) {
        acc[m][n] = __builtin_amdgcn_mfma_f32_16x16x32_bf16(ah[m], bh[n], acc[m][n], 0, 0, 0);
        acc[m][n] = __builtin_amdgcn_mfma_f32_16x16x32_bf16(ah[m], bl[n], acc[m][n], 0, 0, 0);
        acc[m][n] = __builtin_amdgcn_mfma_f32_16x16x32_bf16(al[m], bh[n], acc[m][n], 0, 0, 0);
      }
    __syncthreads();
  }

  const int orow = bm * 128 + wr * 64 + ((lane >> 4) << 2);
  const int ocol = bn * 128 + wc * 64 + (lane & 15);
#pragma unroll
  for (int n = 0; n < 4; ++n)
#pragma unroll
    for (int m = 0; m < 4; ++m)
#pragma unroll
      for (int r = 0; r < 4; ++r) {
        const size_t o = (size_t)(orow + m * 16 + r) * OUT_D + ocol + n * 16;
        out[o] += acc[m][n][r];
      }
}

// ================= fallback (small ws): fp32 path =================
__global__ __launch_bounds__(256) void k_router_fb(
    const float* __restrict__ x, const float* __restrict__ rW, const float* __restrict__ rb,
    const float* __restrict__ A, const int* __restrict__ emap, float* __restrict__ hwf)
{
  __shared__ float4 xs4[1024];
  __shared__ float outs[144];
  __shared__ float wsc[8];
  const int t = blockIdx.x;
  const int tid = threadIdx.x;
  const float4* xr = (const float4*)(x + (size_t)t * 4096);
#pragma unroll
  for (int i = 0; i < 4; ++i) xs4[tid + i * 256] = xr[tid + i * 256];
  __syncthreads();

  const int lane = tid & 63, wid = tid >> 6;
  for (int o = wid; o < 143; o += 4) {
    const float4* wrow = (const float4*)((o < 15) ? (rW + (size_t)o * 4096)
                                                  : (A + (size_t)(o - 15) * 4096));
    float s = 0.f;
    for (int i = lane; i < 1024; i += 64) {
      float4 a = xs4[i];
      float4 w = wrow[i];
      s = fmaf(a.x, w.x, fmaf(a.y, w.y, fmaf(a.z, w.z, fmaf(a.w, w.w, s))));
    }
#pragma unroll
    for (int off = 32; off; off >>= 1) s += __shfl_down(s, off, 64);
    if (lane == 0) outs[o] = s + ((o < 15) ? rb[o] : 0.f);
  }
  __syncthreads();
  if (tid == 0) {
    float p[15];
    float mx = outs[0];
#pragma unroll
    for (int i = 1; i < 15; ++i) mx = fmaxf(mx, outs[i]);
    float sum = 0.f;
#pragma unroll
    for (int i = 0; i < 15; ++i) { p[i] = __expf(outs[i] - mx); sum += p[i]; }
    const float inv = 1.f / sum;
    float w[8] = {0, 0, 0, 0, 0, 0, 0, 0};
    unsigned sel = 0;
    for (int j = 0; j < 8; ++j) {
      int bi = -1; float bv = -1.f;
      for (int i = 0; i < 15; ++i)
        if (!((sel >> i) & 1u) && p[i] > bv) { bv = p[i]; bi = i; }
      sel |= 1u << bi;
      w[emap[bi]] += p[bi] * inv;
    }
#pragma unroll
    for (int e = 0; e < 8; ++e) wsc[e] = w[e] * 2.0f;
  }
  __syncthreads();
  if (tid < 128) hwf[(size_t)t * 128 + tid] = outs[15 + tid] * wsc[tid >> 4];
}

__global__ __launch_bounds__(256) void k_gemm_fb(
    const float* __restrict__ X, const float* __restrict__ W, const float* __restrict__ bias,
    const float* __restrict__ hwf, const float* __restrict__ btf, float* __restrict__ out)
{
  __shared__ float sA[64][33], sB[64][33];
  const int bm = blockIdx.x >> 6;
  const int bn = blockIdx.x & 63;
  const int tid = threadIdx.x;
  const int tr = tid >> 4, tc = tid & 15;
  float acc[4][4] = {};

  const float* Aps[2] = {X, hwf};
  const float* Bps[2] = {W, btf};
  const int lds_[2] = {4096, 128};
  const int Ks[2] = {4096, 128};

  for (int ph = 0; ph < 2; ++ph) {
    const float* Ap = Aps[ph];
    const float* Bp = Bps[ph];
    const int ld = lds_[ph];
    for (int k0 = 0; k0 < Ks[ph]; k0 += 32) {
      __syncthreads();
      for (int i = tid; i < 512; i += 256) {
        const int r = i >> 3, c = (i & 7) << 2;
        float4 va = *(const float4*)&Ap[(size_t)(bm * 64 + r) * ld + k0 + c];
        sA[r][c] = va.x; sA[r][c + 1] = va.y; sA[r][c + 2] = va.z; sA[r][c + 3] = va.w;
        float4 vb = *(const float4*)&Bp[(size_t)(bn * 64 + r) * ld + k0 + c];
        sB[r][c] = vb.x; sB[r][c + 1] = vb.y; sB[r][c + 2] = vb.z; sB[r][c + 3] = vb.w;
      }
      __syncthreads();
      for (int k = 0; k < 32; ++k) {
        float a[4], bvv[4];
#pragma unroll
        for (int i = 0; i < 4; ++i) a[i] = sA[tr * 4 + i][k];
#pragma unroll
        for (int j = 0; j < 4; ++j) bvv[j] = sB[tc * 4 + j][k];
#pragma unroll
        for (int i = 0; i < 4; ++i)
#pragma unroll
          for (int j = 0; j < 4; ++j) acc[i][j] = fmaf(a[i], bvv[j], acc[i][j]);
      }
    }
  }
#pragma unroll
  for (int i = 0; i < 4; ++i)
#pragma unroll
    for (int j = 0; j < 4; ++j)
      out[(size_t)(bm * 64 + tr * 4 + i) * OUT_D + bn * 64 + tc * 4 + j] =
          acc[i][j] + bias[bn * 64 + tc * 4 + j];
}

// ---------- launch ----------
extern "C" void kernel_launch(void* const* d_in, const int* in_sizes, int n_in,
                              void* d_out, int out_size, void* d_ws, size_t ws_size,
                              hipStream_t stream) {
  const float* x    = (const float*)d_in[0];
  const float* bW   = (const float*)d_in[1];
  const float* bb   = (const float*)d_in[2];
  const float* rW   = (const float*)d_in[3];
  const float* rb   = (const float*)d_in[4];
  const float* A    = (const float*)d_in[5];
  const float* Bm   = (const float*)d_in[6];
  const int*   emap = (const int*)d_in[7];
  float* out = (float*)d_out;

  // ws layout (fast path): 209,977,344 B total
  const size_t SZ_XH  = (size_t)BT * KX * 2;       // 67,108,864
  const size_t SZ_WH  = (size_t)NW * KX * 2;       // 34,603,008
  const size_t SZ_XL  = (size_t)BT * 128 * 2;      //  2,097,152
  const size_t SZ_BT  = (size_t)OUT_D * 128 * 2;   //  1,048,576
  const size_t SZ_WSC = (size_t)BT * 8 * 4;        //    262,144
  const size_t need = 2 * SZ_XH + 2 * SZ_WH + 2 * SZ_XL + 2 * SZ_BT + SZ_WSC;
  char* ws = (char*)d_ws;

  if (ws_size >= need) {
    u16* Xh  = (u16*)ws;
    u16* Xl  = (u16*)(ws + SZ_XH);
    u16* Wh  = (u16*)(ws + 2 * SZ_XH);
    u16* Wl  = (u16*)(ws + 2 * SZ_XH + SZ_WH);
    u16* XLh = (u16*)(ws + 2 * SZ_XH + 2 * SZ_WH);
    u16* XLl = (u16*)(ws + 2 * SZ_XH + 2 * SZ_WH + SZ_XL);
    u16* Bth = (u16*)(ws + 2 * SZ_XH + 2 * SZ_WH + 2 * SZ_XL);
    u16* Btl = (u16*)(ws + 2 * SZ_XH + 2 * SZ_WH + 2 * SZ_XL + SZ_BT);
    float* wsc = (float*)(ws + 2 * SZ_XH + 2 * SZ_WH + 2 * SZ_XL + 2 * SZ_BT);

    k_split_w<<<dim3(4224), dim3(256), 0, stream>>>(bW, A, Wh, Wl);
    k_split_x<<<dim3(1024), dim3(256), 0, stream>>>(x, rW, rb, emap, Xh, Xl, wsc);
    k_bt<<<dim3(2048), dim3(256), 0, stream>>>(Bm, Bth, Btl, nullptr, 1);
    k_gemm1<<<dim3(2112), dim3(256), 0, stream>>>(Xh, Xl, Wh, Wl, bb, wsc, out, XLh, XLl);
    k_gemm2<<<dim3(2048), dim3(256), 0, stream>>>(XLh, XLl, Bth, Btl, out);
  } else {
    float* hwf = (float*)ws;                            // 4,194,304
    float* btf = (float*)(ws + (size_t)BT * 128 * 4);   // 2,097,152
    k_router_fb<<<dim3(BT), dim3(256), 0, stream>>>(x, rW, rb, A, emap, hwf);
    k_bt<<<dim3(2048), dim3(256), 0, stream>>>(Bm, nullptr, nullptr, btf, 0);
    k_gemm_fb<<<dim3(8192), dim3(256), 0, stream>>>(x, bW, bb, hwf, btf, out);
  }
}

// Round 5
// 1279.965 us; speedup vs baseline: 1.4787x; 1.1701x over previous
//
#include <hip/hip_runtime.h>
#include <cstdint>

typedef unsigned short u16;
typedef short s16x8 __attribute__((ext_vector_type(8)));
typedef float f32x4 __attribute__((ext_vector_type(4)));
typedef unsigned short u16x4 __attribute__((ext_vector_type(4)));

#define KX    4096
#define BT    8192
#define OUT_D 4096
#define NW    4224           // W rows: 4096 base + 128 A

// ---------- helpers ----------
__device__ __forceinline__ u16 bf16_rne(float v) {
  unsigned u = __float_as_uint(v);
  return (u16)((u + 0x7FFFu + ((u >> 16) & 1u)) >> 16);
}
__device__ __forceinline__ float bf16_f(u16 h) { return __uint_as_float(((unsigned)h) << 16); }

__device__ __forceinline__ void gl16(const void* g, void* l) {
  auto gp = reinterpret_cast<const __attribute__((address_space(1))) unsigned int*>(
      reinterpret_cast<uintptr_t>(g));
  auto lp = reinterpret_cast<__attribute__((address_space(3))) unsigned int*>(
      reinterpret_cast<uintptr_t>(l));
  __builtin_amdgcn_global_load_lds(gp, lp, 16, 0, 0);
}

#define MFMA(a, b, c) __builtin_amdgcn_mfma_f32_16x16x32_bf16((a), (b), (c), 0, 0, 0)

// softmax over 15 logits + top-8 + expert combine weights (×SCALING=2)
__device__ __forceinline__ void route_w(const float* s, const float* rb,
                                        const int* emap, float* wsc, int t) {
  float p[15]; float mx = -1e30f;
#pragma unroll
  for (int i = 0; i < 15; ++i) { p[i] = s[i] + rb[i]; mx = fmaxf(mx, p[i]); }
  float sum = 0.f;
#pragma unroll
  for (int i = 0; i < 15; ++i) { p[i] = __expf(p[i] - mx); sum += p[i]; }
  const float inv = 1.f / sum;
  float w[8] = {0, 0, 0, 0, 0, 0, 0, 0};
  unsigned sel = 0;
  for (int j = 0; j < 8; ++j) {          // top-8 of 15; strict > keeps first index on ties
    int bi = -1; float bv = -1.f;
    for (int i = 0; i < 15; ++i)
      if (!((sel >> i) & 1u) && p[i] > bv) { bv = p[i]; bi = i; }
    sel |= 1u << bi;
    w[emap[bi]] += p[bi] * inv;
  }
#pragma unroll
  for (int e = 0; e < 8; ++e) wsc[t * 8 + e] = w[e] * 2.0f;
}

// ---------- k_split_x: x -> Xh/Xl, fused router logits -> wsc ----------
__global__ __launch_bounds__(256) void k_split_x(
    const float* __restrict__ x, const float* __restrict__ rW, const float* __restrict__ rb,
    const int* __restrict__ emap,
    u16* __restrict__ Xh, u16* __restrict__ Xl, float* __restrict__ wsc)
{
  const int tid = threadIdx.x;
  const int blk = blockIdx.x;

  const float4* xs = (const float4*)x + (size_t)blk * 8192;
#pragma unroll 4
  for (int j = 0; j < 32; ++j) {
    const int i = j * 256 + tid;
    float4 v = xs[i];
    float vv[4] = {v.x, v.y, v.z, v.w};
    u16x4 hv, lv;
#pragma unroll
    for (int q = 0; q < 4; ++q) {
      u16 h = bf16_rne(vv[q]);
      hv[q] = h; lv[q] = bf16_rne(vv[q] - bf16_f(h));
    }
    const size_t e0 = ((size_t)blk * 8192 + i) * 4;
    *(u16x4*)&Xh[e0] = hv;
    *(u16x4*)&Xl[e0] = lv;
  }

  const int lane = tid & 63, wid = tid >> 6;
  const int t0 = blk * 8 + wid * 2;
  const float4* xr0 = (const float4*)x + (size_t)t0 * 1024;
  const float4* xr1 = xr0 + 1024;
  const float4* w4 = (const float4*)rW;
  float s0[15], s1[15];
#pragma unroll
  for (int o = 0; o < 15; ++o) { s0[o] = 0.f; s1[o] = 0.f; }
  for (int it = 0; it < 16; ++it) {
    const int off = it * 64 + lane;
    float4 xa = xr0[off];
    float4 xb = xr1[off];
#pragma unroll
    for (int o = 0; o < 15; ++o) {
      float4 w = w4[o * 1024 + off];
      s0[o] = fmaf(xa.x, w.x, fmaf(xa.y, w.y, fmaf(xa.z, w.z, fmaf(xa.w, w.w, s0[o]))));
      s1[o] = fmaf(xb.x, w.x, fmaf(xb.y, w.y, fmaf(xb.z, w.z, fmaf(xb.w, w.w, s1[o]))));
    }
  }
#pragma unroll
  for (int o = 0; o < 15; ++o) {
#pragma unroll
    for (int d = 32; d; d >>= 1) {
      s0[o] += __shfl_down(s0[o], d, 64);
      s1[o] += __shfl_down(s1[o], d, 64);
    }
  }
  if (lane == 0) {
    route_w(s0, rb, emap, wsc, t0);
    route_w(s1, rb, emap, wsc, t0 + 1);
  }
}

// ---------- k_split_w: [base_W(4096) ; A(128)] -> Wh/Wl [4224][4096] ----------
__global__ __launch_bounds__(256) void k_split_w(
    const float* __restrict__ bW, const float* __restrict__ A,
    u16* __restrict__ dh, u16* __restrict__ dl)
{
  const long n4 = (long)NW * KX / 4;
  for (long i = (long)blockIdx.x * 256 + threadIdx.x; i < n4; i += (long)gridDim.x * 256) {
    float4 v = (i < 4194304) ? ((const float4*)bW)[i] : ((const float4*)A)[i - 4194304];
    float vv[4] = {v.x, v.y, v.z, v.w};
    u16x4 hv, lv;
#pragma unroll
    for (int j = 0; j < 4; ++j) {
      u16 h = bf16_rne(vv[j]);
      hv[j] = h; lv[j] = bf16_rne(vv[j] - bf16_f(h));
    }
    *(u16x4*)&dh[i * 4] = hv;
    *(u16x4*)&dl[i * 4] = lv;
  }
}

// ---------- k_bt: B [8][4096][16] -> Bt [4096][128] hi/lo (fast) or fp32 (fallback) ----------
__global__ __launch_bounds__(256) void k_bt(
    const float* __restrict__ B, u16* __restrict__ dh, u16* __restrict__ dl,
    float* __restrict__ btf, int fast)
{
  const int idx = blockIdx.x * 256 + threadIdx.x;
  if (idx >= 8 * 4096 * 16) return;
  const int e = idx >> 16;
  const int o = (idx >> 4) & 4095;
  const int r = idx & 15;
  const float v = B[idx];
  const int off = o * 128 + e * 16 + r;
  if (fast) {
    u16 h = bf16_rne(v);
    dh[off] = h; dl[off] = bf16_rne(v - bf16_f(h));
  } else {
    btf[off] = v;
  }
}

// ---------- k_gemm1: 256x256-tile, 8-wave, 6-phase counted-vmcnt bf16x3 GEMM ----------
// [out | h] = X · W^T. Supertile = BK=32 real-k, 4 staging units {Ah,Bh,Bl,Al} of 16KB.
// LDS 128 KiB (2 supertile dbuf). T2 source-pre-swizzle: blk ^= ((row>>1)&3) on 16B blocks.
// vmcnt(4)+barrier at phases 0,2 only (loads never drained to 0 in steady state).
__global__ __launch_bounds__(512, 2) void k_gemm1(
    const u16* __restrict__ Xh, const u16* __restrict__ Xl,
    const u16* __restrict__ Wh, const u16* __restrict__ Wl,
    const float* __restrict__ bias, const float* __restrict__ wsc,
    float* __restrict__ out, u16* __restrict__ XLh, u16* __restrict__ XLl)
{
  __shared__ __align__(16) u16 lds[2][4][8192];   // [buf][piece: 0=Ah 1=Bh 2=Al 3=Bl][256x32]
  const int tid = threadIdx.x;
  const int lane = tid & 63;
  const int wid = tid >> 6;
  const int l15 = lane & 15;
  const int wr = wid >> 2;           // 2 M-wave rows
  const int wc = wid & 3;            // 4 N-wave cols

  // bijective XCD swizzle (grid = 544, 544 % 8 == 0)
  const int bI = blockIdx.x;
  const int cpx = gridDim.x >> 3;    // 68
  const int wg = (bI & 7) * cpx + (bI >> 3);
  const int bm = wg / 17;            // 32 M-tiles
  const int bn = wg % 17;            // 17 N-tiles (16 base + 1 lora/garbage)

  // staging source addresses (per-thread), with T2 inverse-swizzle on the k-chunk
  const size_t kcs = (size_t)(((tid & 3) ^ ((tid >> 3) & 3)) << 3);
  const size_t offA0 = (size_t)(bm * 256 + (tid >> 2)) * KX + kcs;
  const size_t offA1 = offA0 + (size_t)128 * KX;
  const size_t offB0 = (size_t)(bn * 256 + (tid >> 2)) * KX + kcs;
  const size_t offB1 = offB0 + (size_t)128 * KX;
  const int ldsw = wid * 512;        // wave-uniform LDS elem base (lane*16B implicit)

#define STG(buf, p, P, o0, o1, kb)                       \
  gl16(P + (o0) + (kb), &lds[buf][p][ldsw]);             \
  gl16(P + (o1) + (kb), &lds[buf][p][4096 + ldsw]);

  // fragment read addrs (swizzled): elem = row*32 + ((lane>>4)^((l15>>1)&3))*8
  const int swk = ((lane >> 4) ^ ((l15 >> 1) & 3)) << 3;
  const int aBase = (wr * 128 + l15) * 32 + swk;
  const int bBase = (wc * 64 + l15) * 32 + swk;

  f32x4 acc[8][4] = {};

  // prologue: stage supertile 0 in consumption order Ah, Bh, Bl, Al
  STG(0, 0, Xh, offA0, offA1, 0);
  STG(0, 1, Wh, offB0, offB1, 0);
  STG(0, 3, Wl, offB0, offB1, 0);
  STG(0, 2, Xl, offA0, offA1, 0);

  int cur = 0;
  for (int st = 0; st < 127; ++st) {
    const int nxt = cur ^ 1;
    const size_t kb = (size_t)(st + 1) * 32;
    const u16* Ah_ = lds[cur][0];
    const u16* Bh_ = lds[cur][1];
    const u16* Al_ = lds[cur][2];
    const u16* Bl_ = lds[cur][3];

    // ---- ph0: wait Ah,Bh; stage next-Ah; MFMA ah·bh n=0,1
    asm volatile("s_waitcnt vmcnt(4)" ::: "memory");
    asm volatile("s_barrier" ::: "memory");
    STG(nxt, 0, Xh, offA0, offA1, kb);
    s16x8 ah[8];
#pragma unroll
    for (int m = 0; m < 8; ++m) ah[m] = *(const s16x8*)&Ah_[aBase + m * 512];
    s16x8 bh0 = *(const s16x8*)&Bh_[bBase];
    s16x8 bh1 = *(const s16x8*)&Bh_[bBase + 512];
    __builtin_amdgcn_s_setprio(1);
#pragma unroll
    for (int m = 0; m < 8; ++m) acc[m][0] = MFMA(ah[m], bh0, acc[m][0]);
#pragma unroll
    for (int m = 0; m < 8; ++m) acc[m][1] = MFMA(ah[m], bh1, acc[m][1]);
    __builtin_amdgcn_s_setprio(0);

    // ---- ph1: stage next-Bh; MFMA ah·bh n=2,3
    STG(nxt, 1, Wh, offB0, offB1, kb);
    s16x8 bh2 = *(const s16x8*)&Bh_[bBase + 1024];
    s16x8 bh3 = *(const s16x8*)&Bh_[bBase + 1536];
    __builtin_amdgcn_s_setprio(1);
#pragma unroll
    for (int m = 0; m < 8; ++m) acc[m][2] = MFMA(ah[m], bh2, acc[m][2]);
#pragma unroll
    for (int m = 0; m < 8; ++m) acc[m][3] = MFMA(ah[m], bh3, acc[m][3]);
    __builtin_amdgcn_s_setprio(0);

    // ---- ph2: wait Bl,Al; stage next-Bl; MFMA ah·bl n=0,1
    asm volatile("s_waitcnt vmcnt(4)" ::: "memory");
    asm volatile("s_barrier" ::: "memory");
    STG(nxt, 3, Wl, offB0, offB1, kb);
    {
      s16x8 bl0 = *(const s16x8*)&Bl_[bBase];
      s16x8 bl1 = *(const s16x8*)&Bl_[bBase + 512];
      __builtin_amdgcn_s_setprio(1);
#pragma unroll
      for (int m = 0; m < 8; ++m) acc[m][0] = MFMA(ah[m], bl0, acc[m][0]);
#pragma unroll
      for (int m = 0; m < 8; ++m) acc[m][1] = MFMA(ah[m], bl1, acc[m][1]);
      __builtin_amdgcn_s_setprio(0);
    }

    // ---- ph3: stage next-Al; MFMA ah·bl n=2,3
    STG(nxt, 2, Xl, offA0, offA1, kb);
    {
      s16x8 bl2 = *(const s16x8*)&Bl_[bBase + 1024];
      s16x8 bl3 = *(const s16x8*)&Bl_[bBase + 1536];
      __builtin_amdgcn_s_setprio(1);
#pragma unroll
      for (int m = 0; m < 8; ++m) acc[m][2] = MFMA(ah[m], bl2, acc[m][2]);
#pragma unroll
      for (int m = 0; m < 8; ++m) acc[m][3] = MFMA(ah[m], bl3, acc[m][3]);
      __builtin_amdgcn_s_setprio(0);
    }

    // ---- ph4/ph5: MFMA al·bh all n
    {
      s16x8 al[8];
#pragma unroll
      for (int m = 0; m < 8; ++m) al[m] = *(const s16x8*)&Al_[aBase + m * 512];
      __builtin_amdgcn_s_setprio(1);
#pragma unroll
      for (int m = 0; m < 8; ++m) acc[m][0] = MFMA(al[m], bh0, acc[m][0]);
#pragma unroll
      for (int m = 0; m < 8; ++m) acc[m][1] = MFMA(al[m], bh1, acc[m][1]);
#pragma unroll
      for (int m = 0; m < 8; ++m) acc[m][2] = MFMA(al[m], bh2, acc[m][2]);
#pragma unroll
      for (int m = 0; m < 8; ++m) acc[m][3] = MFMA(al[m], bh3, acc[m][3]);
      __builtin_amdgcn_s_setprio(0);
    }
    cur = nxt;
  }

  // ---- peeled last supertile (st=127): no staging, waits 4 / 2 / 0
  {
    const u16* Ah_ = lds[cur][0];
    const u16* Bh_ = lds[cur][1];
    const u16* Al_ = lds[cur][2];
    const u16* Bl_ = lds[cur][3];
    asm volatile("s_waitcnt vmcnt(4)" ::: "memory");
    asm volatile("s_barrier" ::: "memory");
    s16x8 ah[8];
#pragma unroll
    for (int m = 0; m < 8; ++m) ah[m] = *(const s16x8*)&Ah_[aBase + m * 512];
    s16x8 bh0 = *(const s16x8*)&Bh_[bBase];
    s16x8 bh1 = *(const s16x8*)&Bh_[bBase + 512];
    s16x8 bh2 = *(const s16x8*)&Bh_[bBase + 1024];
    s16x8 bh3 = *(const s16x8*)&Bh_[bBase + 1536];
#pragma unroll
    for (int m = 0; m < 8; ++m) acc[m][0] = MFMA(ah[m], bh0, acc[m][0]);
#pragma unroll
    for (int m = 0; m < 8; ++m) acc[m][1] = MFMA(ah[m], bh1, acc[m][1]);
#pragma unroll
    for (int m = 0; m < 8; ++m) acc[m][2] = MFMA(ah[m], bh2, acc[m][2]);
#pragma unroll
    for (int m = 0; m < 8; ++m) acc[m][3] = MFMA(ah[m], bh3, acc[m][3]);
    asm volatile("s_waitcnt vmcnt(2)" ::: "memory");
    asm volatile("s_barrier" ::: "memory");
#pragma unroll
    for (int n = 0; n < 4; ++n) {
      s16x8 bl = *(const s16x8*)&Bl_[bBase + n * 512];
#pragma unroll
      for (int m = 0; m < 8; ++m) acc[m][n] = MFMA(ah[m], bl, acc[m][n]);
    }
    asm volatile("s_waitcnt vmcnt(0)" ::: "memory");
    asm volatile("s_barrier" ::: "memory");
    {
      s16x8 al[8];
#pragma unroll
      for (int m = 0; m < 8; ++m) al[m] = *(const s16x8*)&Al_[aBase + m * 512];
#pragma unroll
      for (int m = 0; m < 8; ++m) acc[m][0] = MFMA(al[m], bh0, acc[m][0]);
#pragma unroll
      for (int m = 0; m < 8; ++m) acc[m][1] = MFMA(al[m], bh1, acc[m][1]);
#pragma unroll
      for (int m = 0; m < 8; ++m) acc[m][2] = MFMA(al[m], bh2, acc[m][2]);
#pragma unroll
      for (int m = 0; m < 8; ++m) acc[m][3] = MFMA(al[m], bh3, acc[m][3]);
    }
  }

  // ---- epilogue: C/D layout col=lane&15, row=(lane>>4)*4+r (m89-verified)
  const int orow0 = bm * 256 + wr * 128 + ((lane >> 4) << 2);
  if (bn < 16) {
    const int ocol0 = bn * 256 + wc * 64 + l15;
#pragma unroll
    for (int n = 0; n < 4; ++n) {
      const int col = ocol0 + n * 16;
      const float bv = bias[col];
#pragma unroll
      for (int m = 0; m < 8; ++m)
#pragma unroll
        for (int r = 0; r < 4; ++r)
          out[(size_t)(orow0 + m * 16 + r) * OUT_D + col] = acc[m][n][r] + bv;
    }
  } else {
    const int j0 = wc * 64 + l15;    // lora-h column index (valid if < 128)
#pragma unroll
    for (int n = 0; n < 4; ++n) {
      const int j = j0 + n * 16;
      if (j < 128) {
        const int e = j >> 4;
#pragma unroll
        for (int m = 0; m < 8; ++m)
#pragma unroll
          for (int r = 0; r < 4; ++r) {
            const int t = orow0 + m * 16 + r;
            const float v = acc[m][n][r] * wsc[t * 8 + e];
            u16 h = bf16_rne(v);
            XLh[t * 128 + j] = h;
            XLl[t * 128 + j] = bf16_rne(v - bf16_f(h));
          }
      }
    }
  }
#undef STG
}

// ---------- k_gemm2: out += XL · Bt^T (bf16x3), K=128 ----------
__global__ __launch_bounds__(256) void k_gemm2(
    const u16* __restrict__ XLh, const u16* __restrict__ XLl,
    const u16* __restrict__ Bth, const u16* __restrict__ Btl,
    float* __restrict__ out)
{
  __shared__ __align__(16) u16 lAh[4096], lAl[4096], lBh[4096], lBl[4096];
  const int tid = threadIdx.x;
  const int lane = tid & 63;
  const int wid = tid >> 6;

  const int bI = blockIdx.x;
  const int cpx = gridDim.x >> 3;
  const int wg = (bI & 7) * cpx + (bI >> 3);
  const int bm = wg >> 5;
  const int bn = wg & 31;
  const int wr = wid >> 1, wc = wid & 1;

  const int srow = tid >> 2;
  const int skc = (tid & 3) << 3;
  const size_t a0 = (size_t)(bm * 128 + srow) * 128 + skc;
  const size_t a1 = a0 + (size_t)64 * 128;
  const size_t b0 = (size_t)(bn * 128 + srow) * 128 + skc;
  const size_t b1 = b0 + (size_t)64 * 128;
  const int d0 = wid * 512;
  const int d1 = 2048 + wid * 512;

  const int ra = (wr * 64 + (lane & 15)) * 32 + ((lane >> 4) << 3);
  const int rb = (wc * 64 + (lane & 15)) * 32 + ((lane >> 4) << 3);

  f32x4 acc[4][4] = {};

  for (int kt = 0; kt < 4; ++kt) {
    const int ko = kt * 32;
    gl16(XLh + a0 + ko, lAh + d0);
    gl16(XLh + a1 + ko, lAh + d1);
    gl16(XLl + a0 + ko, lAl + d0);
    gl16(XLl + a1 + ko, lAl + d1);
    gl16(Bth + b0 + ko, lBh + d0);
    gl16(Bth + b1 + ko, lBh + d1);
    gl16(Btl + b0 + ko, lBl + d0);
    gl16(Btl + b1 + ko, lBl + d1);
    asm volatile("s_waitcnt vmcnt(0)" ::: "memory");
    __syncthreads();

    s16x8 ah[4], al[4], bh[4], bl[4];
#pragma unroll
    for (int m = 0; m < 4; ++m) {
      ah[m] = *(const s16x8*)&lAh[ra + m * 512];
      al[m] = *(const s16x8*)&lAl[ra + m * 512];
    }
#pragma unroll
    for (int n = 0; n < 4; ++n) {
      bh[n] = *(const s16x8*)&lBh[rb + n * 512];
      bl[n] = *(const s16x8*)&lBl[rb + n * 512];
    }
#pragma unroll
    for (int m = 0; m < 4; ++m)
#pragma unroll
      for (int n = 0; n < 4; ++n) {
        acc[m][n] = MFMA(ah[m], bh[n], acc[m][n]);
        acc[m][n] = MFMA(ah[m], bl[n], acc[m][n]);
        acc[m][n] = MFMA(al[m], bh[n], acc[m][n]);
      }
    __syncthreads();
  }

  const int orow = bm * 128 + wr * 64 + ((lane >> 4) << 2);
  const int ocol = bn * 128 + wc * 64 + (lane & 15);
#pragma unroll
  for (int n = 0; n < 4; ++n)
#pragma unroll
    for (int m = 0; m < 4; ++m)
#pragma unroll
      for (int r = 0; r < 4; ++r) {
        const size_t o = (size_t)(orow + m * 16 + r) * OUT_D + ocol + n * 16;
        out[o] += acc[m][n][r];
      }
}

// ================= fallback (small ws): fp32 path =================
__global__ __launch_bounds__(256) void k_router_fb(
    const float* __restrict__ x, const float* __restrict__ rW, const float* __restrict__ rb,
    const float* __restrict__ A, const int* __restrict__ emap, float* __restrict__ hwf)
{
  __shared__ float4 xs4[1024];
  __shared__ float outs[144];
  __shared__ float wsc[8];
  const int t = blockIdx.x;
  const int tid = threadIdx.x;
  const float4* xr = (const float4*)(x + (size_t)t * 4096);
#pragma unroll
  for (int i = 0; i < 4; ++i) xs4[tid + i * 256] = xr[tid + i * 256];
  __syncthreads();

  const int lane = tid & 63, wid = tid >> 6;
  for (int o = wid; o < 143; o += 4) {
    const float4* wrow = (const float4*)((o < 15) ? (rW + (size_t)o * 4096)
                                                  : (A + (size_t)(o - 15) * 4096));
    float s = 0.f;
    for (int i = lane; i < 1024; i += 64) {
      float4 a = xs4[i];
      float4 w = wrow[i];
      s = fmaf(a.x, w.x, fmaf(a.y, w.y, fmaf(a.z, w.z, fmaf(a.w, w.w, s))));
    }
#pragma unroll
    for (int off = 32; off; off >>= 1) s += __shfl_down(s, off, 64);
    if (lane == 0) outs[o] = s + ((o < 15) ? rb[o] : 0.f);
  }
  __syncthreads();
  if (tid == 0) {
    float p[15];
    float mx = outs[0];
#pragma unroll
    for (int i = 1; i < 15; ++i) mx = fmaxf(mx, outs[i]);
    float sum = 0.f;
#pragma unroll
    for (int i = 0; i < 15; ++i) { p[i] = __expf(outs[i] - mx); sum += p[i]; }
    const float inv = 1.f / sum;
    float w[8] = {0, 0, 0, 0, 0, 0, 0, 0};
    unsigned sel = 0;
    for (int j = 0; j < 8; ++j) {
      int bi = -1; float bv = -1.f;
      for (int i = 0; i < 15; ++i)
        if (!((sel >> i) & 1u) && p[i] > bv) { bv = p[i]; bi = i; }
      sel |= 1u << bi;
      w[emap[bi]] += p[bi] * inv;
    }
#pragma unroll
    for (int e = 0; e < 8; ++e) wsc[e] = w[e] * 2.0f;
  }
  __syncthreads();
  if (tid < 128) hwf[(size_t)t * 128 + tid] = outs[15 + tid] * wsc[tid >> 4];
}

__global__ __launch_bounds__(256) void k_gemm_fb(
    const float* __restrict__ X, const float* __restrict__ W, const float* __restrict__ bias,
    const float* __restrict__ hwf, const float* __restrict__ btf, float* __restrict__ out)
{
  __shared__ float sA[64][33], sB[64][33];
  const int bm = blockIdx.x >> 6;
  const int bn = blockIdx.x & 63;
  const int tid = threadIdx.x;
  const int tr = tid >> 4, tc = tid & 15;
  float acc[4][4] = {};

  const float* Aps[2] = {X, hwf};
  const float* Bps[2] = {W, btf};
  const int lds_[2] = {4096, 128};
  const int Ks[2] = {4096, 128};

  for (int ph = 0; ph < 2; ++ph) {
    const float* Ap = Aps[ph];
    const float* Bp = Bps[ph];
    const int ld = lds_[ph];
    for (int k0 = 0; k0 < Ks[ph]; k0 += 32) {
      __syncthreads();
      for (int i = tid; i < 512; i += 256) {
        const int r = i >> 3, c = (i & 7) << 2;
        float4 va = *(const float4*)&Ap[(size_t)(bm * 64 + r) * ld + k0 + c];
        sA[r][c] = va.x; sA[r][c + 1] = va.y; sA[r][c + 2] = va.z; sA[r][c + 3] = va.w;
        float4 vb = *(const float4*)&Bp[(size_t)(bn * 64 + r) * ld + k0 + c];
        sB[r][c] = vb.x; sB[r][c + 1] = vb.y; sB[r][c + 2] = vb.z; sB[r][c + 3] = vb.w;
      }
      __syncthreads();
      for (int k = 0; k < 32; ++k) {
        float a[4], bvv[4];
#pragma unroll
        for (int i = 0; i < 4; ++i) a[i] = sA[tr * 4 + i][k];
#pragma unroll
        for (int j = 0; j < 4; ++j) bvv[j] = sB[tc * 4 + j][k];
#pragma unroll
        for (int i = 0; i < 4; ++i)
#pragma unroll
          for (int j = 0; j < 4; ++j) acc[i][j] = fmaf(a[i], bvv[j], acc[i][j]);
      }
    }
  }
#pragma unroll
  for (int i = 0; i < 4; ++i)
#pragma unroll
    for (int j = 0; j < 4; ++j)
      out[(size_t)(bm * 64 + tr * 4 + i) * OUT_D + bn * 64 + tc * 4 + j] =
          acc[i][j] + bias[bn * 64 + tc * 4 + j];
}

// ---------- launch ----------
extern "C" void kernel_launch(void* const* d_in, const int* in_sizes, int n_in,
                              void* d_out, int out_size, void* d_ws, size_t ws_size,
                              hipStream_t stream) {
  const float* x    = (const float*)d_in[0];
  const float* bW   = (const float*)d_in[1];
  const float* bb   = (const float*)d_in[2];
  const float* rW   = (const float*)d_in[3];
  const float* rb   = (const float*)d_in[4];
  const float* A    = (const float*)d_in[5];
  const float* Bm   = (const float*)d_in[6];
  const int*   emap = (const int*)d_in[7];
  float* out = (float*)d_out;

  // ws layout (fast path): 209,977,344 B total (identical to round-2, proven to fit)
  const size_t SZ_XH  = (size_t)BT * KX * 2;       // 67,108,864
  const size_t SZ_WH  = (size_t)NW * KX * 2;       // 34,603,008
  const size_t SZ_XL  = (size_t)BT * 128 * 2;      //  2,097,152
  const size_t SZ_BT  = (size_t)OUT_D * 128 * 2;   //  1,048,576
  const size_t SZ_WSC = (size_t)BT * 8 * 4;        //    262,144
  const size_t need = 2 * SZ_XH + 2 * SZ_WH + 2 * SZ_XL + 2 * SZ_BT + SZ_WSC;
  char* ws = (char*)d_ws;

  if (ws_size >= need) {
    u16* Xh  = (u16*)ws;
    u16* Xl  = (u16*)(ws + SZ_XH);
    u16* Wh  = (u16*)(ws + 2 * SZ_XH);
    u16* Wl  = (u16*)(ws + 2 * SZ_XH + SZ_WH);
    u16* XLh = (u16*)(ws + 2 * SZ_XH + 2 * SZ_WH);
    u16* XLl = (u16*)(ws + 2 * SZ_XH + 2 * SZ_WH + SZ_XL);
    u16* Bth = (u16*)(ws + 2 * SZ_XH + 2 * SZ_WH + 2 * SZ_XL);
    u16* Btl = (u16*)(ws + 2 * SZ_XH + 2 * SZ_WH + 2 * SZ_XL + SZ_BT);
    float* wsc = (float*)(ws + 2 * SZ_XH + 2 * SZ_WH + 2 * SZ_XL + 2 * SZ_BT);

    // NOTE: k_gemm1's bn=16 tile reads B rows 4224..4351, i.e. 1 MB past Wh/Wl end —
    // still inside ws (followed by Wl/XLh); values are garbage but those output
    // columns are discarded in the epilogue. Keeps ws at the proven size.
    k_split_w<<<dim3(4224), dim3(256), 0, stream>>>(bW, A, Wh, Wl);
    k_split_x<<<dim3(1024), dim3(256), 0, stream>>>(x, rW, rb, emap, Xh, Xl, wsc);
    k_bt<<<dim3(2048), dim3(256), 0, stream>>>(Bm, Bth, Btl, nullptr, 1);
    k_gemm1<<<dim3(544), dim3(512), 0, stream>>>(Xh, Xl, Wh, Wl, bb, wsc, out, XLh, XLl);
    k_gemm2<<<dim3(2048), dim3(256), 0, stream>>>(XLh, XLl, Bth, Btl, out);
  } else {
    float* hwf = (float*)ws;
    float* btf = (float*)(ws + (size_t)BT * 128 * 4);
    k_router_fb<<<dim3(BT), dim3(256), 0, stream>>>(x, rW, rb, A, emap, hwf);
    k_bt<<<dim3(2048), dim3(256), 0, stream>>>(Bm, nullptr, nullptr, btf, 0);
    k_gemm_fb<<<dim3(8192), dim3(256), 0, stream>>>(x, bW, bb, hwf, btf, out);
  }
}